// Round 1
// 195.795 us; speedup vs baseline: 1.0132x; 1.0132x over previous
//
#include <hip/hip_runtime.h>

#define D 128
#define CAP 64
#define OVF_CAP 1024

typedef short bf16x8 __attribute__((ext_vector_type(8)));
typedef float f32x4 __attribute__((ext_vector_type(4)));

__device__ __forceinline__ unsigned short f2bf(float f) {
  unsigned u = __builtin_bit_cast(unsigned, f);
  unsigned r = (u + 0x7fffu + ((u >> 16) & 1u)) >> 16;
  return (unsigned short)r;
}
__device__ __forceinline__ float bflo(unsigned r) {
  return __builtin_bit_cast(float, r << 16);
}
__device__ __forceinline__ float bfhi(unsigned r) {
  return __builtin_bit_cast(float, r & 0xffff0000u);
}
__device__ __forceinline__ float lrelu(float t) {
  return t >= 0.f ? t : 0.2f * t;
}
// LDS byte-offset swizzle: XOR bits 8-10 into bits 4-6.  Write side (fixed row m)
// spreads the 64 lanes' 4B stores over all 32 banks (was 16-way on 4 banks);
// read side stays a full-coverage b128 pattern (bijective within each 1 KB tile).
__device__ __forceinline__ int swz(int b) { return b ^ (((b >> 8) & 7) << 4); }

// ---------------- kernels ----------------

// setup: qid=-1, deg/den=0, counters=0, pack Wcat->bf16 fragments, calc_v (block 0)
__global__ void k_setup(const float* __restrict__ Wp, const float* __restrict__ asp,
                        const float* __restrict__ adp, const float* __restrict__ Wc,
                        const float* __restrict__ asc, const float* __restrict__ adc,
                        const float* __restrict__ bp, const float* __restrict__ bc,
                        const float* __restrict__ bl, const float* __restrict__ Wl,
                        const float* __restrict__ Wr,
                        float* __restrict__ v, unsigned short* __restrict__ wpack,
                        int* __restrict__ qid, int* __restrict__ counters,
                        int* __restrict__ deg5, int N, int S5) {
  int i = blockIdx.x * blockDim.x + threadIdx.x;
  int stride = gridDim.x * blockDim.x;
  for (int k = i; k < N; k += stride) qid[k] = -1;
  for (int k = i; k < S5; k += stride) deg5[k] = 0;   // degP/C/R + denP/denC (0.0f bits)
  if (i < 16) counters[i] = 0;

  // wpack[((kt*8+nt)*64+lane)*8+j] = Wcat[kt*32+(lane>>4)*8+j][nt*16+(lane&15)]
  for (int idx = i; idx < 16 * 8 * 64 * 8; idx += stride) {
    int j    = idx & 7;
    int lane = (idx >> 3) & 63;
    int nt   = (idx >> 9) & 7;
    int kt   = idx >> 12;
    int o = kt >> 2;
    int c = (kt & 3) * 32 + (lane >> 4) * 8 + j;
    int n = nt * 16 + (lane & 15);
    const float* W = (o == 0) ? Wp : (o == 1) ? Wc : (o == 2) ? Wl : Wr;
    wpack[idx] = f2bf(W[c * D + n]);
  }

  if (blockIdx.x == 0 && threadIdx.x < 128) {
    int k = threadIdx.x;
    float s0 = 0.f, s1 = 0.f, s2 = 0.f, s3 = 0.f;
    for (int d = 0; d < D; ++d) {
      float wp = Wp[k * D + d], wc = Wc[k * D + d];
      s0 += wp * asp[d]; s1 += wp * adp[d];
      s2 += wc * asc[d]; s3 += wc * adc[d];
    }
    v[k] = s0; v[D + k] = s1; v[2 * D + k] = s2; v[3 * D + k] = s3;
    v[4 * D + k] = bp[k] + bc[k] + bl[k];
  }
}

// build_qid (wave-aggregated unique-id alloc) + attention scalars + self-loop
// weights + bf16 emb copy. One wave handles TWO nodes: 32 lanes x float4 per row.
__global__ void k_pre(const int* __restrict__ s, int* __restrict__ qid,
                      int* __restrict__ uniq, int* __restrict__ counters, int S,
                      const float* __restrict__ emb, const float* __restrict__ v,
                      float* __restrict__ a_sp, float* __restrict__ a_dp,
                      float* __restrict__ a_sc, float* __restrict__ a_dc,
                      float* __restrict__ selfP, float* __restrict__ selfC,
                      unsigned* __restrict__ ebf, int N) {
  int gtid = blockIdx.x * blockDim.x + threadIdx.x;
  int lane = threadIdx.x & 63;
  if (gtid < S) {
    int n = s[gtid];
    bool won = (atomicCAS(&qid[n], -1, -2) == -1);
    unsigned long long mask = __ballot(won);
    if (mask != 0ull) {
      int leader = __builtin_ctzll(mask);
      int base = 0;
      if (lane == leader) base = atomicAdd(&counters[0], __popcll(mask));
      base = __shfl(base, leader);          // one same-address atomic per wave
      if (won) {
        int u = base + __popcll(mask & ((1ull << lane) - 1ull));
        uniq[u] = n;
        qid[n] = u;
      }
    }
  }
  int node = (gtid >> 6) * 2 + (lane >> 5);
  int c = lane & 31;                       // float4 chunk within row
  if (node >= N) return;
  float4 x4 = ((const float4*)(emb + (size_t)node * D))[c];
  uint2 p;
  p.x = ((unsigned)f2bf(x4.x)) | (((unsigned)f2bf(x4.y)) << 16);
  p.y = ((unsigned)f2bf(x4.z)) | (((unsigned)f2bf(x4.w)) << 16);
  ((uint2*)ebf)[(size_t)node * 32 + c] = p;
  float4 v0 = ((const float4*)(v))[c];
  float4 v1 = ((const float4*)(v + D))[c];
  float4 v2 = ((const float4*)(v + 2 * D))[c];
  float4 v3 = ((const float4*)(v + 3 * D))[c];
  float s0 = x4.x * v0.x + x4.y * v0.y + x4.z * v0.z + x4.w * v0.w;
  float s1 = x4.x * v1.x + x4.y * v1.y + x4.z * v1.z + x4.w * v1.w;
  float s2 = x4.x * v2.x + x4.y * v2.y + x4.z * v2.z + x4.w * v2.w;
  float s3 = x4.x * v3.x + x4.y * v3.y + x4.z * v3.z + x4.w * v3.w;
#pragma unroll
  for (int o = 16; o > 0; o >>= 1) {
    s0 += __shfl_down(s0, o);
    s1 += __shfl_down(s1, o);
    s2 += __shfl_down(s2, o);
    s3 += __shfl_down(s3, o);
  }
  if (c == 0) {
    a_sp[node] = s0; a_dp[node] = s1; a_sc[node] = s2; a_dc[node] = s3;
    selfP[node] = __expf(lrelu(s0 + s1));
    selfC[node] = __expf(lrelu(s2 + s3));
  }
}

// direct-bucket filter (blockIdx.y = relation).  GAT relations additionally
// compute the edge weight here (edge-parallel, latency hidden by streaming)
// and accumulate the softmax denominator via float atomics:
// bkt[u*CAP+pos] = (src, w),  den[u] += w  (den covers ALL edges incl. overflow).
__global__ void __launch_bounds__(256) k_filter(
    const int* __restrict__ eiP, const int* __restrict__ eiC,
    const int* __restrict__ eiR, const int* __restrict__ qid,
    int2* __restrict__ bktP, int2* __restrict__ bktC, int* __restrict__ bktR,
    int* __restrict__ degP, int* __restrict__ degC, int* __restrict__ degR,
    float* __restrict__ denP, float* __restrict__ denC,
    const float* __restrict__ a_sp, const float* __restrict__ a_dp,
    const float* __restrict__ a_sc, const float* __restrict__ a_dc,
    int2* __restrict__ ovf, int* __restrict__ counters, int E) {
  int rel = blockIdx.y;
  const int* ei = (rel == 0) ? eiP : (rel == 1) ? eiC : eiR;
  int e = blockIdx.x * 256 + threadIdx.x;
  if (e >= E) return;
  int dst = ei[E + e];
  int u = qid[dst];
  if (u < 0) return;
  int src = ei[e];
  int* deg = (rel == 0) ? degP : (rel == 1) ? degC : degR;
  int pos = atomicAdd(&deg[u], 1);
  if (rel == 2) {
    if (pos < CAP) {
      bktR[u * CAP + pos] = src;
    } else {
      int o = atomicAdd(&counters[6], 1);
      if (o < OVF_CAP) { int2 tt; tt.x = src; tt.y = u; ovf[2 * OVF_CAP + o] = tt; }
    }
  } else {
    const float* a_s = (rel == 0) ? a_sp : a_sc;
    const float* a_d = (rel == 0) ? a_dp : a_dc;
    float wgt = __expf(lrelu(a_s[src] + a_d[dst]));
    atomicAdd((rel == 0) ? &denP[u] : &denC[u], wgt);
    if (pos < CAP) {
      int2 tt; tt.x = src; tt.y = __builtin_bit_cast(int, wgt);
      ((rel == 0) ? bktP : bktC)[u * CAP + pos] = tt;
    } else {
      int o = atomicAdd(&counters[4 + rel], 1);
      if (o < OVF_CAP) { int2 tt; tt.x = src; tt.y = u; ovf[rel * OVF_CAP + o] = tt; }
    }
  }
}

// fused gather+final: per 16-u tile, 8 waves x 2 u-rows each across all 3
// relations (weights precomputed: chain is bucket-load -> shfl -> ebf gathers),
// stage z-rows into swizzled LDS A-fragments, then MFMA against packed Wcat.
// outU[u] = ([zP|zC|zR|x]@Wcat)/3 + bias/3.
__global__ void __launch_bounds__(512, 4) k_fused(
    const int2* __restrict__ bktP, const int2* __restrict__ bktC,
    const int* __restrict__ bktR,
    const int* __restrict__ degP, const int* __restrict__ degC,
    const int* __restrict__ degR,
    const float* __restrict__ denP, const float* __restrict__ denC,
    const float* __restrict__ a_sp, const float* __restrict__ a_dp,
    const float* __restrict__ a_sc, const float* __restrict__ a_dc,
    const float* __restrict__ selfP, const float* __restrict__ selfC,
    const unsigned* __restrict__ ebf, const float* __restrict__ emb,
    const int* __restrict__ uniq, const int* __restrict__ counters,
    const int2* __restrict__ ovf, const float* __restrict__ vvec,
    const unsigned short* __restrict__ wpack, float* __restrict__ outU) {
  __shared__ __align__(16) unsigned short A_lds[16 * 64 * 8];   // 16 KB
  int U = counters[0];
  int u0 = blockIdx.x * 16;
  if (u0 >= U) return;
  int tid = threadIdx.x;
  int w = tid >> 6;
  int lane = tid & 63;

  int Lc[3];
#pragma unroll
  for (int r = 0; r < 3; ++r) {
    int L = counters[4 + r];
    Lc[r] = (L > OVF_CAP) ? OVF_CAP : L;
  }

#pragma unroll
  for (int t = 0; t < 2; ++t) {
    int m = 2 * w + t;
    int u = u0 + m;
    float2 z[4];
    if (u < U) {
      int n = uniq[u];
      float2 x2 = ((const float2*)(emb + (size_t)n * D))[lane];
#pragma unroll
      for (int r = 0; r < 3; ++r) {
        int dg = ((r == 0) ? degP : (r == 1) ? degC : degR)[u];
        int mc = (dg < CAP) ? dg : CAP;
        int srcl = 0;
        float wl = 0.f;
        if (r < 2) {
          if (lane < mc) {
            int2 sw_ = ((r == 0) ? bktP : bktC)[u * CAP + lane];
            srcl = sw_.x;
            wl = __builtin_bit_cast(float, sw_.y);
          }
        } else {
          if (lane < mc) { srcl = bktR[u * CAP + lane]; wl = 1.f; }
        }
        float2 a; a.x = 0.f; a.y = 0.f;
        int i = 0;
        for (; i + 4 <= mc; i += 4) {
          int s0 = __shfl(srcl, i),     s1 = __shfl(srcl, i + 1);
          int s2 = __shfl(srcl, i + 2), s3 = __shfl(srcl, i + 3);
          float w0 = __shfl(wl, i),     w1 = __shfl(wl, i + 1);
          float w2 = __shfl(wl, i + 2), w3 = __shfl(wl, i + 3);
          unsigned r0 = ebf[(size_t)s0 * 64 + lane];
          unsigned r1 = ebf[(size_t)s1 * 64 + lane];
          unsigned r2 = ebf[(size_t)s2 * 64 + lane];
          unsigned r3 = ebf[(size_t)s3 * 64 + lane];
          a.x += w0 * bflo(r0) + w1 * bflo(r1) + w2 * bflo(r2) + w3 * bflo(r3);
          a.y += w0 * bfhi(r0) + w1 * bfhi(r1) + w2 * bfhi(r2) + w3 * bfhi(r3);
        }
        for (; i < mc; ++i) {
          int si = __shfl(srcl, i);
          float wi = __shfl(wl, i);
          unsigned rr = ebf[(size_t)si * 64 + lane];
          a.x += wi * bflo(rr);
          a.y += wi * bfhi(rr);
        }
        // overflow numerator fixup (statistically never taken; den already full)
        if (dg > CAP) {
          const float* a_s = (r == 0) ? a_sp : a_sc;
          float adn = (r == 0) ? a_dp[n] : (r == 1) ? a_dc[n] : 0.f;
          for (int l = 0; l < Lc[r]; ++l) {
            int2 ov = ovf[r * OVF_CAP + l];
            if (ov.y == u) {
              float wv = 1.f;
              if (r < 2) wv = __expf(lrelu(a_s[ov.x] + adn));
              unsigned rr = ebf[(size_t)ov.x * 64 + lane];
              a.x += wv * bflo(rr);
              a.y += wv * bfhi(rr);
            }
          }
        }
        if (r == 2) {
          float dgc = (float)dg; if (dgc < 1.f) dgc = 1.f;
          float rc = 1.f / dgc;
          a.x *= rc; a.y *= rc;
        }
        z[r] = a;
      }
      float wP = selfP[n];
      float rP = 1.f / (denP[u] + wP);
      float wC = selfC[n];
      float rC = 1.f / (denC[u] + wC);
      z[0].x = (z[0].x + wP * x2.x) * rP; z[0].y = (z[0].y + wP * x2.y) * rP;
      z[1].x = (z[1].x + wC * x2.x) * rC; z[1].y = (z[1].y + wC * x2.y) * rC;
      z[3] = x2;
    } else {
      z[0].x = 0.f; z[0].y = 0.f; z[1] = z[0]; z[2] = z[0]; z[3] = z[0];
    }
    // LDS A-fragment write (swizzled): columns c=2*lane, 2*lane+1 of operand o
    int ktc = lane >> 4;
    int q = (lane >> 2) & 3;
    int j0 = 2 * (lane & 3);
#pragma unroll
    for (int o = 0; o < 4; ++o) {
      int kt = o * 4 + ktc;
      unsigned pk = ((unsigned)f2bf(z[o].x)) | (((unsigned)f2bf(z[o].y)) << 16);
      int off = ((kt * 64 + q * 16 + m) * 8 + j0) * 2;
      *(unsigned*)((char*)A_lds + swz(off)) = pk;
    }
  }
  __syncthreads();

  f32x4 acc = {0.f, 0.f, 0.f, 0.f};
  const bf16x8* wp = (const bf16x8*)wpack;
#pragma unroll
  for (int kt = 0; kt < 16; ++kt) {
    bf16x8 a = *(const bf16x8*)((const char*)A_lds + swz((kt * 64 + lane) * 16));
    bf16x8 b = wp[(kt * 8 + w) * 64 + lane];
    acc = __builtin_amdgcn_mfma_f32_16x16x32_bf16(a, b, acc, 0, 0, 0);
  }

  int col = w * 16 + (lane & 15);
  int r0 = (lane >> 4) * 4;
  float bv = vvec[4 * D + col] * (1.f / 3.f);
#pragma unroll
  for (int reg = 0; reg < 4; ++reg) {
    int u = u0 + r0 + reg;
    if (u < U) outU[(size_t)u * D + col] = acc[reg] * (1.f / 3.f) + bv;
  }
}

// pure gather (bias and /3 already folded into outU)
__global__ void k_gather(const int* __restrict__ s, const int* __restrict__ qid,
                         const float* __restrict__ outU, float* __restrict__ out, int S) {
  int idx = blockIdx.x * blockDim.x + threadIdx.x;
  if (idx >= S * D) return;
  int i = idx >> 7;
  int d = idx & (D - 1);
  int u = qid[s[i]];
  out[idx] = outU[(size_t)u * D + d];
}

// ---------------- launch ----------------

extern "C" void kernel_launch(void* const* d_in, const int* in_sizes, int n_in,
                              void* d_out, int out_size, void* d_ws, size_t ws_size,
                              hipStream_t stream) {
  const int*   s   = (const int*)d_in[0];
  const int*   eip = (const int*)d_in[3];
  const int*   eic = (const int*)d_in[4];
  const int*   eir = (const int*)d_in[5];
  const float* emb = (const float*)d_in[6];
  const float* Wp  = (const float*)d_in[7];
  const float* asp = (const float*)d_in[8];
  const float* adp = (const float*)d_in[9];
  const float* bp  = (const float*)d_in[10];
  const float* Wc  = (const float*)d_in[11];
  const float* asc = (const float*)d_in[12];
  const float* adc = (const float*)d_in[13];
  const float* bc  = (const float*)d_in[14];
  const float* Wl  = (const float*)d_in[15];
  const float* bl  = (const float*)d_in[16];
  const float* Wr  = (const float*)d_in[17];
  float* out = (float*)d_out;

  const int S = in_sizes[0];
  const int E = in_sizes[3] / 2;
  const int N = in_sizes[6] / D;

  char* base = (char*)d_ws;
  size_t off = 0;
  auto carve = [&](size_t bytes) -> char* {
    char* q = base + off;
    off += (bytes + 255) & ~(size_t)255;
    return q;
  };
  float*    a_sp     = (float*)carve((size_t)N * 4);
  float*    a_dp     = (float*)carve((size_t)N * 4);
  float*    a_sc     = (float*)carve((size_t)N * 4);
  float*    a_dc     = (float*)carve((size_t)N * 4);
  float*    selfP    = (float*)carve((size_t)N * 4);
  float*    selfC    = (float*)carve((size_t)N * 4);
  int*      qid      = (int*)carve((size_t)N * 4);
  unsigned* ebf      = (unsigned*)carve((size_t)N * 64 * 4);   // 25.6 MB bf16 emb
  int*      uniq     = (int*)carve((size_t)S * 4);
  int*      counters = (int*)carve(64);    // [0]=U [4..6]=overflow counts
  float*    vvec     = (float*)carve(5 * D * 4);
  unsigned short* wpack = (unsigned short*)carve((size_t)16 * 8 * 64 * 8 * 2);  // 128 KB
  float*    outU     = (float*)carve((size_t)S * D * 4);
  int*      degP     = (int*)carve((size_t)S * 4);      // degP/C/R + denP/C contiguous
  int*      degC     = (int*)carve((size_t)S * 4);
  int*      degR     = (int*)carve((size_t)S * 4);
  float*    denP     = (float*)carve((size_t)S * 4);
  float*    denC     = (float*)carve((size_t)S * 4);
  int2*     bktP     = (int2*)carve((size_t)S * CAP * 8);   // (src, w) pairs
  int2*     bktC     = (int2*)carve((size_t)S * CAP * 8);
  int*      bktR     = (int*)carve((size_t)S * CAP * 4);
  int2*     ovf      = (int2*)carve((size_t)3 * OVF_CAP * 8);
  (void)ws_size; (void)n_in; (void)out_size;

  k_setup<<<256, 256, 0, stream>>>(Wp, asp, adp, Wc, asc, adc, bp, bc, bl, Wl, Wr,
                                   vvec, wpack, qid, counters, degP, N, 5 * S);

  k_pre<<<(N * 32 + 255) / 256, 256, 0, stream>>>(s, qid, uniq, counters, S,
                                                  emb, vvec, a_sp, a_dp, a_sc, a_dc,
                                                  selfP, selfC, ebf, N);

  k_filter<<<dim3((E + 255) / 256, 3), 256, 0, stream>>>(
      eip, eic, eir, qid, bktP, bktC, bktR, degP, degC, degR, denP, denC,
      a_sp, a_dp, a_sc, a_dc, ovf, counters, E);

  k_fused<<<(S + 15) / 16, 512, 0, stream>>>(
      bktP, bktC, bktR, degP, degC, degR, denP, denC,
      a_sp, a_dp, a_sc, a_dc, selfP, selfC, ebf, emb, uniq, counters, ovf,
      vvec, wpack, outU);

  k_gather<<<(S * D + 255) / 256, 256, 0, stream>>>(s, qid, outU, out, S);
}